// Round 6
// baseline (138.570 us; speedup 1.0000x reference)
//
#include <hip/hip_runtime.h>

#define B_SZ 4
#define LQ 4096
#define LKV 4096
#define DIN 256
#define DOUT 128
#define KVBLK 64
#define NT (LKV / KVBLK)
#define BLQ (B_SZ * LQ)

typedef unsigned short u16;
typedef __attribute__((ext_vector_type(8))) short bf16x8;
typedef __attribute__((ext_vector_type(4))) float f32x4;

union Bf8Pack {
  u16 u[8];
  bf16x8 v;
};
union U16x4Pack {
  u16 u[4];
  uint2 v;
};

__device__ __forceinline__ u16 f2bf(float x) {
  unsigned u = __float_as_uint(x);
  u += 0x7fffu + ((u >> 16) & 1u);
  return (u16)(u >> 16);
}

__device__ __forceinline__ unsigned cvt_pk_bf16(float lo, float hi) {
  unsigned r;
  asm("v_cvt_pk_bf16_f32 %0, %1, %2" : "=v"(r) : "v"(lo), "v"(hi));
  return r;
}

__device__ __forceinline__ void gload_lds16(const u16* g, u16* l) {
  __builtin_amdgcn_global_load_lds(
      (__attribute__((address_space(1))) unsigned int*)g,
      (__attribute__((address_space(3))) unsigned int*)l, 16, 0, 0);
}

// ---------- weight transpose + bf16 convert: Wt[3][128][256], WoT[128][128] ----------
__global__ __launch_bounds__(256) void wtrans_kernel(
    const float* __restrict__ Wq, const float* __restrict__ Wk,
    const float* __restrict__ Wv, const float* __restrict__ Wo,
    u16* __restrict__ Wt, u16* __restrict__ WoT) {
  const int gid = blockIdx.x * 256 + threadIdx.x;
  if (gid < 3 * DOUT * DIN) {
    const int which = gid / (DOUT * DIN);
    const int r = gid % (DOUT * DIN);
    const int n = r >> 8;
    const int k = r & 255;
    const float* W = (which == 0) ? Wq : (which == 1) ? Wk : Wv;
    Wt[gid] = f2bf(W[k * DOUT + n]);
  } else {
    const int r = gid - 3 * DOUT * DIN;
    if (r < DOUT * DOUT) {
      const int n = r >> 7;
      const int k = r & 127;
      WoT[r] = f2bf(Wo[k * DOUT + n]);
    }
  }
}

// ---------- QKV projection via MFMA ----------
__global__ __launch_bounds__(256) void qkv_proj_mfma(
    const float* __restrict__ ligand, const float* __restrict__ pocket,
    const float* __restrict__ bq, const float* __restrict__ bk,
    const float* __restrict__ bv, const u16* __restrict__ Wt,
    u16* __restrict__ Qb, u16* __restrict__ Kb, u16* __restrict__ Vt) {
  const int which = blockIdx.y;
  const int row0 = blockIdx.x * 64;
  const int tid = threadIdx.x;
  const int wid = tid >> 6;
  const int lane = tid & 63;
  const int lg = lane >> 4, lr = lane & 15;
  const float* __restrict__ src = (which == 0) ? ligand : pocket;
  const int m = row0 + wid * 16 + lr;

  bf16x8 sfrag[8];
#pragma unroll
  for (int ks = 0; ks < 8; ++ks) {
    const float* p = src + (size_t)m * DIN + ks * 32 + lg * 8;
    const float4 a = *(const float4*)p;
    const float4 b = *(const float4*)(p + 4);
    Bf8Pack pk;
    pk.u[0] = f2bf(a.x); pk.u[1] = f2bf(a.y); pk.u[2] = f2bf(a.z); pk.u[3] = f2bf(a.w);
    pk.u[4] = f2bf(b.x); pk.u[5] = f2bf(b.y); pk.u[6] = f2bf(b.z); pk.u[7] = f2bf(b.w);
    sfrag[ks] = pk.v;
  }

  const u16* __restrict__ Wtw = Wt + (size_t)which * DOUT * DIN;

  if (which < 2) {
    const float* __restrict__ bias = (which == 0) ? bq : bk;
    u16* __restrict__ dst = (which == 0) ? Qb : Kb;
    // Q pre-scaled by 1/sqrt(128) * log2(e) so flash uses exp2 directly.
    const float qscale = (float)(0.08838834764831845 * 1.4426950408889634);
#pragma unroll
    for (int dt = 0; dt < 8; ++dt) {
      f32x4 acc = (f32x4){0.f, 0.f, 0.f, 0.f};
#pragma unroll
      for (int ks = 0; ks < 8; ++ks) {
        const bf16x8 wf =
            *(const bf16x8*)(Wtw + (size_t)(dt * 16 + lr) * DIN + ks * 32 + lg * 8);
        acc = __builtin_amdgcn_mfma_f32_16x16x32_bf16(wf, sfrag[ks], acc, 0, 0, 0);
      }
      U16x4Pack st;
#pragma unroll
      for (int j = 0; j < 4; ++j) {
        const int d = dt * 16 + lg * 4 + j;
        float v = acc[j] + bias[d];
        if (which == 0) v *= qscale;
        st.u[j] = f2bf(v);
      }
      *(uint2*)(dst + (size_t)m * DOUT + dt * 16 + lg * 4) = st.v;
    }
  } else {
    const int batch = row0 >> 12;
    const int kvbase = (row0 & 4095) + wid * 16 + lg * 4;
#pragma unroll
    for (int dt = 0; dt < 8; ++dt) {
      f32x4 acc = (f32x4){0.f, 0.f, 0.f, 0.f};
#pragma unroll
      for (int ks = 0; ks < 8; ++ks) {
        const bf16x8 wf =
            *(const bf16x8*)(Wtw + (size_t)(dt * 16 + lr) * DIN + ks * 32 + lg * 8);
        acc = __builtin_amdgcn_mfma_f32_16x16x32_bf16(sfrag[ks], wf, acc, 0, 0, 0);
      }
      const int d = dt * 16 + lr;
      const float b = bv[d];
      U16x4Pack st;
#pragma unroll
      for (int j = 0; j < 4; ++j) st.u[j] = f2bf(acc[j] + b);
      *(uint2*)(Vt + ((size_t)batch * DOUT + d) * LKV + kvbase) = st.v;
    }
  }
}

// ---------------- Flash attention: fragment-ordered LDS, counted-vmcnt schedule ----------------
// Block = 256 threads = 4 waves; wave owns G*16 q-rows; QBLK = 64*G.
// Per iter: [vmcnt(0); bar; STAGEV(t)+STAGEK(t+1); QK; softmax; vmcnt(4); bar; PV]
// No drain: prefetch loads stay in flight across raw s_barriers (T3/T4).
template <int G>
__global__ __launch_bounds__(256) void flash_attn_kernel(
    const u16* __restrict__ Qb, const u16* __restrict__ Kb,
    const u16* __restrict__ Vt, float* __restrict__ Opart,
    float* __restrict__ Ml, int niter) {
  __shared__ __align__(16) u16 Ks[2 * KVBLK * 128];
  __shared__ __align__(16) u16 Vs[128 * KVBLK];
  __shared__ __align__(16) unsigned Psw[4 * G * 512];

  const int batch = blockIdx.y;
  const int split = blockIdx.z;
  const int q0 = blockIdx.x * (64 * G);
  const int tid = threadIdx.x;
  const int wid = tid >> 6;
  const int lane = tid & 63;
  const int lg = lane >> 4;
  const int lr = lane & 15;
  const int t0 = split * niter;

  // staging source offsets (u16 elements), hoisted
  int koff[4], voff[4];
#pragma unroll
  for (int i = 0; i < 4; ++i) {
    const int c = i * 256 + tid;
    koff[i] = (((c >> 6) & 3) * 16 + (c & 15)) * 128 + (c >> 8) * 32 +
              ((c >> 4) & 3) * 8;
    voff[i] = (((c >> 6) & 7) * 16 + (c & 15)) * LKV + (c >> 9) * 32 +
              ((c >> 4) & 3) * 8;
  }
  const u16* KbB = Kb + (size_t)batch * LKV * 128 + (size_t)t0 * KVBLK * 128;
  const u16* VtB = Vt + (size_t)batch * 128 * LKV + t0 * KVBLK;

#define STAGEK(buf, t)                                                       \
  {                                                                          \
    _Pragma("unroll") for (int i = 0; i < 4; ++i)                            \
        gload_lds16(KbB + (t) * (KVBLK * 128) + koff[i],                     \
                    Ks + (buf) * (KVBLK * 128) + (i * 256 + tid) * 8);       \
  }
#define STAGEV(t)                                                            \
  {                                                                          \
    _Pragma("unroll") for (int i = 0; i < 4; ++i)                            \
        gload_lds16(VtB + (t) * KVBLK + voff[i], Vs + (i * 256 + tid) * 8);  \
  }

  // Q fragments in registers
  const u16* Qw = Qb + ((size_t)batch * LQ + q0 + wid * 16 * G) * 128;
  bf16x8 qf[G][4];
#pragma unroll
  for (int g = 0; g < G; ++g)
#pragma unroll
    for (int ks = 0; ks < 4; ++ks)
      qf[g][ks] =
          *(const bf16x8*)(Qw + (size_t)(g * 16 + lr) * 128 + ks * 32 + lg * 8);

  f32x4 oacc[G][8];
#pragma unroll
  for (int g = 0; g < G; ++g)
#pragma unroll
    for (int dt = 0; dt < 8; ++dt) oacc[g][dt] = (f32x4){0.f, 0.f, 0.f, 0.f};
  float m_run[G], l_run[G];
#pragma unroll
  for (int g = 0; g < G; ++g) {
    m_run[g] = -1e30f;
    l_run[g] = 0.f;
  }

  // P write addresses (u32 index within wave region), hoisted per ct
  unsigned* Pwave = Psw + wid * (G * 512);
  int pwidx[4];
#pragma unroll
  for (int ct = 0; ct < 4; ++ct)
    pwidx[ct] = (((ct >> 1) * 64 + lr + (((ct * 2 + (lg >> 1)) & 3) << 4)) << 2) +
                (lg & 1) * 2;
  const u16* pread = (const u16*)Pwave + lane * 8;
  const u16* vread = Vs + lane * 8;

  STAGEK(0, 0);

  int cur = 0;
  for (int t = 0; t < niter; ++t) {
    // barrier A: own K(t) loads done; all waves past PV(t-1) (V buf free)
    asm volatile("s_waitcnt vmcnt(0)" ::: "memory");
    __builtin_amdgcn_s_barrier();
    __builtin_amdgcn_sched_barrier(0);

    STAGEV(t);  // 4 loads, waited at barrier B
    const bool pre = (t + 1 < niter);
    if (pre) STAGEK(cur ^ 1, t + 1);  // 4 loads, stay in flight until next iter

    const u16* kread = Ks + cur * (KVBLK * 128) + lane * 8;

    // S^T = K Q^T : sacc[g][ct][j] = S[q=g*16+lr][kv = ct*16 + lg*4 + j]
    f32x4 sacc[G][4];
#pragma unroll
    for (int g = 0; g < G; ++g)
#pragma unroll
      for (int ct = 0; ct < 4; ++ct) sacc[g][ct] = (f32x4){0.f, 0.f, 0.f, 0.f};
    __builtin_amdgcn_s_setprio(1);
#pragma unroll
    for (int ks = 0; ks < 4; ++ks) {
#pragma unroll
      for (int ct = 0; ct < 4; ++ct) {
        const bf16x8 kf = *(const bf16x8*)(kread + (ks * 4 + ct) * 512);
#pragma unroll
        for (int g = 0; g < G; ++g)
          sacc[g][ct] = __builtin_amdgcn_mfma_f32_16x16x32_bf16(kf, qf[g][ks],
                                                               sacc[g][ct], 0, 0, 0);
      }
    }
    __builtin_amdgcn_s_setprio(0);

    // in-register online softmax per q-group (row lane-local + lanes +-16/32)
    float mx[G];
#pragma unroll
    for (int g = 0; g < G; ++g) {
      float m0 = fmaxf(fmaxf(sacc[g][0][0], sacc[g][0][1]),
                       fmaxf(sacc[g][0][2], sacc[g][0][3]));
#pragma unroll
      for (int ct = 1; ct < 4; ++ct)
        m0 = fmaxf(m0, fmaxf(fmaxf(sacc[g][ct][0], sacc[g][ct][1]),
                             fmaxf(sacc[g][ct][2], sacc[g][ct][3])));
      m0 = fmaxf(m0, __shfl_xor(m0, 16, 64));
      m0 = fmaxf(m0, __shfl_xor(m0, 32, 64));
      mx[g] = m0;
    }

    bool small = true;
#pragma unroll
    for (int g = 0; g < G; ++g) small = small && (mx[g] - m_run[g] <= 11.5f);
    if (!__all(small)) {
#pragma unroll
      for (int g = 0; g < G; ++g) {
        const float mn = fmaxf(m_run[g], mx[g]);
        const float corr = exp2f(m_run[g] - mn);
        m_run[g] = mn;
        l_run[g] *= corr;
#pragma unroll
        for (int dt = 0; dt < 8; ++dt)
#pragma unroll
          for (int j = 0; j < 4; ++j) oacc[g][dt][j] *= corr;
      }
    }

#pragma unroll
    for (int g = 0; g < G; ++g) {
      float rs = 0.f;
#pragma unroll
      for (int ct = 0; ct < 4; ++ct) {
        const float p0 = exp2f(sacc[g][ct][0] - m_run[g]);
        const float p1 = exp2f(sacc[g][ct][1] - m_run[g]);
        const float p2 = exp2f(sacc[g][ct][2] - m_run[g]);
        const float p3 = exp2f(sacc[g][ct][3] - m_run[g]);
        rs += (p0 + p1) + (p2 + p3);
        uint2 pw;
        pw.x = cvt_pk_bf16(p0, p1);
        pw.y = cvt_pk_bf16(p2, p3);
        *(uint2*)&Pwave[g * 512 + pwidx[ct]] = pw;
      }
      rs += __shfl_xor(rs, 16, 64);
      rs += __shfl_xor(rs, 32, 64);
      l_run[g] += rs;
    }

    // barrier B: own V(t) loads done (K prefetch stays in flight), all waves' P written
    if (pre) {
      asm volatile("s_waitcnt vmcnt(4)" ::: "memory");
    } else {
      asm volatile("s_waitcnt vmcnt(0)" ::: "memory");
    }
    __builtin_amdgcn_s_barrier();
    __builtin_amdgcn_sched_barrier(0);

    // O^T += V^T P^T
    __builtin_amdgcn_s_setprio(1);
#pragma unroll
    for (int ks2 = 0; ks2 < 2; ++ks2) {
      bf16x8 pf[G];
#pragma unroll
      for (int g = 0; g < G; ++g)
        pf[g] = *(const bf16x8*)(pread + (g * 2 + ks2) * 512);
#pragma unroll
      for (int dt = 0; dt < 8; ++dt) {
        const bf16x8 vf = *(const bf16x8*)(vread + (ks2 * 8 + dt) * 512);
#pragma unroll
        for (int g = 0; g < G; ++g)
          oacc[g][dt] = __builtin_amdgcn_mfma_f32_16x16x32_bf16(vf, pf[g],
                                                               oacc[g][dt], 0, 0, 0);
      }
    }
    __builtin_amdgcn_s_setprio(0);
    cur ^= 1;
  }

  // write fp32 unnormalized partials + (m,l)
#pragma unroll
  for (int g = 0; g < G; ++g) {
    const size_t row = (size_t)split * BLQ + (size_t)batch * LQ + q0 +
                       wid * 16 * G + g * 16 + lr;
    float* Op = Opart + row * 128;
#pragma unroll
    for (int dt = 0; dt < 8; ++dt) {
      float4 o = {oacc[g][dt][0], oacc[g][dt][1], oacc[g][dt][2], oacc[g][dt][3]};
      *(float4*)(Op + dt * 16 + lg * 4) = o;
    }
    if (lane < 16) {
      Ml[row * 2 + 0] = m_run[g];
      Ml[row * 2 + 1] = l_run[g];
    }
  }
#undef STAGEK
#undef STAGEV
}

// ---------- combine KV-splits + output projection via MFMA ----------
__global__ __launch_bounds__(256) void combine_out_proj(
    const float* __restrict__ Opart, const float* __restrict__ Ml,
    const u16* __restrict__ WoT, const float* __restrict__ bo,
    float* __restrict__ out, int nsplit) {
  const int row0 = blockIdx.x * 64;
  const int tid = threadIdx.x;
  const int wid = tid >> 6;
  const int lane = tid & 63;
  const int lg = lane >> 4, lr = lane & 15;
  const int m = row0 + wid * 16 + lr;

  float M = -1e30f;
  for (int s = 0; s < nsplit; ++s)
    M = fmaxf(M, Ml[((size_t)s * BLQ + m) * 2 + 0]);
  float den = 0.f;
  for (int s = 0; s < nsplit; ++s)
    den += Ml[((size_t)s * BLQ + m) * 2 + 1] *
           exp2f(Ml[((size_t)s * BLQ + m) * 2 + 0] - M);
  const float invden = 1.f / den;

  float accO[4][8];
#pragma unroll
  for (int ks = 0; ks < 4; ++ks)
#pragma unroll
    for (int j = 0; j < 8; ++j) accO[ks][j] = 0.f;

  for (int s = 0; s < nsplit; ++s) {
    const float es =
        exp2f(Ml[((size_t)s * BLQ + m) * 2 + 0] - M) * invden;
    const float* Op = Opart + ((size_t)s * BLQ + m) * 128;
#pragma unroll
    for (int ks = 0; ks < 4; ++ks) {
      const float* p = Op + ks * 32 + lg * 8;
      const float4 a = *(const float4*)p;
      const float4 b = *(const float4*)(p + 4);
      accO[ks][0] += es * a.x; accO[ks][1] += es * a.y;
      accO[ks][2] += es * a.z; accO[ks][3] += es * a.w;
      accO[ks][4] += es * b.x; accO[ks][5] += es * b.y;
      accO[ks][6] += es * b.z; accO[ks][7] += es * b.w;
    }
  }

  bf16x8 ofrag[4];
#pragma unroll
  for (int ks = 0; ks < 4; ++ks) {
    Bf8Pack pk;
#pragma unroll
    for (int j = 0; j < 8; ++j) pk.u[j] = f2bf(accO[ks][j]);
    ofrag[ks] = pk.v;
  }

#pragma unroll
  for (int dt = 0; dt < 8; ++dt) {
    f32x4 acc = (f32x4){0.f, 0.f, 0.f, 0.f};
#pragma unroll
    for (int ks = 0; ks < 4; ++ks) {
      const bf16x8 wf =
          *(const bf16x8*)(WoT + (size_t)(dt * 16 + lr) * DOUT + ks * 32 + lg * 8);
      acc = __builtin_amdgcn_mfma_f32_16x16x32_bf16(wf, ofrag[ks], acc, 0, 0, 0);
    }
    float4 o;
    o.x = acc[0] + bo[dt * 16 + lg * 4 + 0];
    o.y = acc[1] + bo[dt * 16 + lg * 4 + 1];
    o.z = acc[2] + bo[dt * 16 + lg * 4 + 2];
    o.w = acc[3] + bo[dt * 16 + lg * 4 + 3];
    *(float4*)(out + (size_t)m * DOUT + dt * 16 + lg * 4) = o;
  }
}

extern "C" void kernel_launch(void* const* d_in, const int* in_sizes, int n_in,
                              void* d_out, int out_size, void* d_ws,
                              size_t ws_size, hipStream_t stream) {
  const float* ligand = (const float*)d_in[0];
  const float* pocket = (const float*)d_in[1];
  const float* Wq = (const float*)d_in[2];
  const float* bq = (const float*)d_in[3];
  const float* Wk = (const float*)d_in[4];
  const float* bk = (const float*)d_in[5];
  const float* Wv = (const float*)d_in[6];
  const float* bv = (const float*)d_in[7];
  const float* Wo = (const float*)d_in[8];
  const float* bo = (const float*)d_in[9];
  float* out = (float*)d_out;

  const size_t MB = 1024 * 1024;
  char* ws = (char*)d_ws;
  u16* Qb = (u16*)(ws);                      // 4 MB
  u16* Kb = (u16*)(ws + 4 * MB);             // 4 MB
  u16* Vt = (u16*)(ws + 8 * MB);             // 4 MB (V^T)
  u16* Wt = (u16*)(ws + 12 * MB);            // 192 KB
  u16* WoT = Wt + 3 * DOUT * DIN;            // 32 KB
  float* Opart = (float*)(ws + 13 * MB);     // ns * 8 MB
  const int ns = (ws_size >= 46 * MB) ? 4 : 2;
  float* Ml = (float*)(ws + 13 * MB + (size_t)ns * 8 * MB);  // ns*128KB

  wtrans_kernel<<<dim3(448), dim3(256), 0, stream>>>(Wq, Wk, Wv, Wo, Wt, WoT);

  dim3 g1(BLQ / 64, 3);
  qkv_proj_mfma<<<g1, dim3(256), 0, stream>>>(ligand, pocket, bq, bk, bv, Wt,
                                              Qb, Kb, Vt);

  if (ns == 4) {
    dim3 g2(LQ / 128, B_SZ, 4);
    flash_attn_kernel<2><<<g2, dim3(256), 0, stream>>>(Qb, Kb, Vt, Opart, Ml,
                                                       NT / 4);
  } else {
    dim3 g2(LQ / 64, B_SZ, 2);
    flash_attn_kernel<1><<<g2, dim3(256), 0, stream>>>(Qb, Kb, Vt, Opart, Ml,
                                                       NT / 2);
  }

  dim3 g3(BLQ / 64);
  combine_out_proj<<<g3, dim3(256), 0, stream>>>(Opart, Ml, WoT, bo, out, ns);
}

// Round 7
// 137.734 us; speedup vs baseline: 1.0061x; 1.0061x over previous
//
#include <hip/hip_runtime.h>

#define B_SZ 4
#define LQ 4096
#define LKV 4096
#define DIN 256
#define DOUT 128
#define KVBLK 32
#define NT (LKV / KVBLK)
#define BLQ (B_SZ * LQ)
#define KTILE (KVBLK * 128)  // u16 elements per K or V tile (8 KB)

typedef unsigned short u16;
typedef __attribute__((ext_vector_type(8))) short bf16x8;
typedef __attribute__((ext_vector_type(4))) float f32x4;

union Bf8Pack {
  u16 u[8];
  bf16x8 v;
};
union U16x4Pack {
  u16 u[4];
  uint2 v;
};

__device__ __forceinline__ u16 f2bf(float x) {
  unsigned u = __float_as_uint(x);
  u += 0x7fffu + ((u >> 16) & 1u);
  return (u16)(u >> 16);
}

__device__ __forceinline__ unsigned cvt_pk_bf16(float lo, float hi) {
  unsigned r;
  asm("v_cvt_pk_bf16_f32 %0, %1, %2" : "=v"(r) : "v"(lo), "v"(hi));
  return r;
}

__device__ __forceinline__ void gload_lds16(const u16* g, u16* l) {
  __builtin_amdgcn_global_load_lds(
      (__attribute__((address_space(1))) unsigned int*)g,
      (__attribute__((address_space(3))) unsigned int*)l, 16, 0, 0);
}

// ---------- weight transpose + bf16 convert: Wt[3][128][256], WoT[128][128] ----------
__global__ __launch_bounds__(256) void wtrans_kernel(
    const float* __restrict__ Wq, const float* __restrict__ Wk,
    const float* __restrict__ Wv, const float* __restrict__ Wo,
    u16* __restrict__ Wt, u16* __restrict__ WoT) {
  const int gid = blockIdx.x * 256 + threadIdx.x;
  if (gid < 3 * DOUT * DIN) {
    const int which = gid / (DOUT * DIN);
    const int r = gid % (DOUT * DIN);
    const int n = r >> 8;
    const int k = r & 255;
    const float* W = (which == 0) ? Wq : (which == 1) ? Wk : Wv;
    Wt[gid] = f2bf(W[k * DOUT + n]);
  } else {
    const int r = gid - 3 * DOUT * DIN;
    if (r < DOUT * DOUT) {
      const int n = r >> 7;
      const int k = r & 127;
      WoT[r] = f2bf(Wo[k * DOUT + n]);
    }
  }
}

// ---------- QKV projection via MFMA ----------
__global__ __launch_bounds__(256) void qkv_proj_mfma(
    const float* __restrict__ ligand, const float* __restrict__ pocket,
    const float* __restrict__ bq, const float* __restrict__ bk,
    const float* __restrict__ bv, const u16* __restrict__ Wt,
    u16* __restrict__ Qb, u16* __restrict__ Kb, u16* __restrict__ Vt) {
  const int which = blockIdx.y;
  const int row0 = blockIdx.x * 64;
  const int tid = threadIdx.x;
  const int wid = tid >> 6;
  const int lane = tid & 63;
  const int lg = lane >> 4, lr = lane & 15;
  const float* __restrict__ src = (which == 0) ? ligand : pocket;
  const int m = row0 + wid * 16 + lr;

  bf16x8 sfrag[8];
#pragma unroll
  for (int ks = 0; ks < 8; ++ks) {
    const float* p = src + (size_t)m * DIN + ks * 32 + lg * 8;
    const float4 a = *(const float4*)p;
    const float4 b = *(const float4*)(p + 4);
    Bf8Pack pk;
    pk.u[0] = f2bf(a.x); pk.u[1] = f2bf(a.y); pk.u[2] = f2bf(a.z); pk.u[3] = f2bf(a.w);
    pk.u[4] = f2bf(b.x); pk.u[5] = f2bf(b.y); pk.u[6] = f2bf(b.z); pk.u[7] = f2bf(b.w);
    sfrag[ks] = pk.v;
  }

  const u16* __restrict__ Wtw = Wt + (size_t)which * DOUT * DIN;

  if (which < 2) {
    const float* __restrict__ bias = (which == 0) ? bq : bk;
    u16* __restrict__ dst = (which == 0) ? Qb : Kb;
    // Q pre-scaled by 1/sqrt(128) * log2(e) so flash uses exp2 directly.
    const float qscale = (float)(0.08838834764831845 * 1.4426950408889634);
#pragma unroll
    for (int dt = 0; dt < 8; ++dt) {
      f32x4 acc = (f32x4){0.f, 0.f, 0.f, 0.f};
#pragma unroll
      for (int ks = 0; ks < 8; ++ks) {
        const bf16x8 wf =
            *(const bf16x8*)(Wtw + (size_t)(dt * 16 + lr) * DIN + ks * 32 + lg * 8);
        acc = __builtin_amdgcn_mfma_f32_16x16x32_bf16(wf, sfrag[ks], acc, 0, 0, 0);
      }
      U16x4Pack st;
#pragma unroll
      for (int j = 0; j < 4; ++j) {
        const int d = dt * 16 + lg * 4 + j;
        float v = acc[j] + bias[d];
        if (which == 0) v *= qscale;
        st.u[j] = f2bf(v);
      }
      *(uint2*)(dst + (size_t)m * DOUT + dt * 16 + lg * 4) = st.v;
    }
  } else {
    const int batch = row0 >> 12;
    const int kvbase = (row0 & 4095) + wid * 16 + lg * 4;
#pragma unroll
    for (int dt = 0; dt < 8; ++dt) {
      f32x4 acc = (f32x4){0.f, 0.f, 0.f, 0.f};
#pragma unroll
      for (int ks = 0; ks < 8; ++ks) {
        const bf16x8 wf =
            *(const bf16x8*)(Wtw + (size_t)(dt * 16 + lr) * DIN + ks * 32 + lg * 8);
        acc = __builtin_amdgcn_mfma_f32_16x16x32_bf16(sfrag[ks], wf, acc, 0, 0, 0);
      }
      const int d = dt * 16 + lr;
      const float b = bv[d];
      U16x4Pack st;
#pragma unroll
      for (int j = 0; j < 4; ++j) st.u[j] = f2bf(acc[j] + b);
      *(uint2*)(Vt + ((size_t)batch * DOUT + d) * LKV + kvbase) = st.v;
    }
  }
}

// ---------------- Flash attention: KVBLK=32, G=2, r4 1-barrier schedule ----------------
// Block = 256 threads = 4 waves; each wave owns 32 q-rows (g=0,1); QBLK = 128.
// LDS K: 2 buf, fragment order: chunk (ks*2+ct), lane holds K[ct*16+lr][ks*32+lg*8..+8]
// LDS V: 2 buf, chunk dt, lane holds V^T[dt*16+lr][lg*8..+8]
// LDS P: per wave, rows (g*16+lr) stride 20 u32 (padded, bank-friendly)
__global__ __launch_bounds__(256) void flash_attn_kernel(
    const u16* __restrict__ Qb, const u16* __restrict__ Kb,
    const u16* __restrict__ Vt, float* __restrict__ Opart,
    float* __restrict__ Ml, int niter) {
  __shared__ __align__(16) u16 Ks[2 * KTILE];
  __shared__ __align__(16) u16 Vs[2 * KTILE];
  __shared__ __align__(16) unsigned Psw[4 * 640];

  const int batch = blockIdx.y;
  const int split = blockIdx.z;
  const int q0 = blockIdx.x * 128;
  const int tid = threadIdx.x;
  const int wid = tid >> 6;
  const int lane = tid & 63;
  const int lg = lane >> 4;
  const int lr = lane & 15;
  const int t0 = split * niter;

  // staging source offsets (u16 elements), hoisted: 512 chunks of 16B each tile
  int koff[2], voff[2];
#pragma unroll
  for (int i = 0; i < 2; ++i) {
    const int c = i * 256 + tid;
    koff[i] = (((c >> 6) & 1) * 16 + (c & 15)) * 128 + (c >> 7) * 32 +
              ((c >> 4) & 3) * 8;
    voff[i] = ((c >> 6) * 16 + (c & 15)) * LKV + ((c >> 4) & 3) * 8;
  }
  const u16* KbB = Kb + (size_t)batch * LKV * 128 + (size_t)t0 * KVBLK * 128;
  const u16* VtB = Vt + (size_t)batch * 128 * LKV + t0 * KVBLK;

#define STAGEKV(buf, t)                                                      \
  {                                                                          \
    _Pragma("unroll") for (int i = 0; i < 2; ++i)                            \
        gload_lds16(KbB + (t) * KTILE + koff[i],                             \
                    Ks + (buf) * KTILE + (i * 256 + tid) * 8);               \
    _Pragma("unroll") for (int i = 0; i < 2; ++i)                            \
        gload_lds16(VtB + (t) * KVBLK + voff[i],                             \
                    Vs + (buf) * KTILE + (i * 256 + tid) * 8);               \
  }

  // Q fragments in registers
  const u16* Qw = Qb + ((size_t)batch * LQ + q0 + wid * 32) * 128;
  bf16x8 qf[2][4];
#pragma unroll
  for (int g = 0; g < 2; ++g)
#pragma unroll
    for (int ks = 0; ks < 4; ++ks)
      qf[g][ks] =
          *(const bf16x8*)(Qw + (size_t)(g * 16 + lr) * 128 + ks * 32 + lg * 8);

  f32x4 oacc[2][8];
#pragma unroll
  for (int g = 0; g < 2; ++g)
#pragma unroll
    for (int dt = 0; dt < 8; ++dt) oacc[g][dt] = (f32x4){0.f, 0.f, 0.f, 0.f};
  float m_run[2], l_run[2];
#pragma unroll
  for (int g = 0; g < 2; ++g) {
    m_run[g] = -1e30f;
    l_run[g] = 0.f;
  }

  unsigned* Pwave = Psw + wid * 640;
  const u16* pread = (const u16*)Pwave;

  STAGEKV(0, 0);
  __syncthreads();

  int cur = 0;
  for (int t = 0; t < niter; ++t) {
    if (t + 1 < niter) STAGEKV(cur ^ 1, t + 1);  // lands during this iter's compute

    const u16* kread = Ks + cur * KTILE + lane * 8;
    const u16* vread = Vs + cur * KTILE + lane * 8;

    // S^T = K Q^T : sacc[g][ct][j] = S[q=g*16+lr][kv = ct*16 + lg*4 + j]
    f32x4 sacc[2][2];
#pragma unroll
    for (int g = 0; g < 2; ++g)
#pragma unroll
      for (int ct = 0; ct < 2; ++ct) sacc[g][ct] = (f32x4){0.f, 0.f, 0.f, 0.f};
#pragma unroll
    for (int ks = 0; ks < 4; ++ks) {
#pragma unroll
      for (int ct = 0; ct < 2; ++ct) {
        const bf16x8 kf = *(const bf16x8*)(kread + (ks * 2 + ct) * 512);
#pragma unroll
        for (int g = 0; g < 2; ++g)
          sacc[g][ct] = __builtin_amdgcn_mfma_f32_16x16x32_bf16(kf, qf[g][ks],
                                                               sacc[g][ct], 0, 0, 0);
      }
    }

    // in-register online softmax (row lane-local across 8 regs + lanes +-16/32)
    float mx[2];
#pragma unroll
    for (int g = 0; g < 2; ++g) {
      float m0 = fmaxf(fmaxf(sacc[g][0][0], sacc[g][0][1]),
                       fmaxf(sacc[g][0][2], sacc[g][0][3]));
      float m1 = fmaxf(fmaxf(sacc[g][1][0], sacc[g][1][1]),
                       fmaxf(sacc[g][1][2], sacc[g][1][3]));
      m0 = fmaxf(m0, m1);
      m0 = fmaxf(m0, __shfl_xor(m0, 16, 64));
      m0 = fmaxf(m0, __shfl_xor(m0, 32, 64));
      mx[g] = m0;
    }

    // defer-max (log2 domain): rescale only on meaningful growth
    if (!__all(fmaxf(mx[0] - m_run[0], mx[1] - m_run[1]) <= 11.5f)) {
#pragma unroll
      for (int g = 0; g < 2; ++g) {
        const float mn = fmaxf(m_run[g], mx[g]);
        const float corr = exp2f(m_run[g] - mn);
        m_run[g] = mn;
        l_run[g] *= corr;
#pragma unroll
        for (int dt = 0; dt < 8; ++dt)
#pragma unroll
          for (int j = 0; j < 4; ++j) oacc[g][dt][j] *= corr;
      }
    }

#pragma unroll
    for (int g = 0; g < 2; ++g) {
      float rs = 0.f;
#pragma unroll
      for (int ct = 0; ct < 2; ++ct) {
        const float p0 = exp2f(sacc[g][ct][0] - m_run[g]);
        const float p1 = exp2f(sacc[g][ct][1] - m_run[g]);
        const float p2 = exp2f(sacc[g][ct][2] - m_run[g]);
        const float p3 = exp2f(sacc[g][ct][3] - m_run[g]);
        rs += (p0 + p1) + (p2 + p3);
        uint2 pw;
        pw.x = cvt_pk_bf16(p0, p1);
        pw.y = cvt_pk_bf16(p2, p3);
        *(uint2*)&Pwave[(g * 16 + lr) * 20 + ct * 8 + lg * 2] = pw;
      }
      rs += __shfl_xor(rs, 16, 64);
      rs += __shfl_xor(rs, 32, 64);
      l_run[g] += rs;
    }

    // O^T += V^T P^T  (pf: lane holds P[q=g*16+lr][kv = lg*8..+8])
#pragma unroll
    for (int g = 0; g < 2; ++g) {
      const bf16x8 pf = *(const bf16x8*)(pread + (g * 16 + lr) * 40 + lg * 8);
#pragma unroll
      for (int dt = 0; dt < 8; ++dt) {
        const bf16x8 vf = *(const bf16x8*)(vread + dt * 512);
        oacc[g][dt] = __builtin_amdgcn_mfma_f32_16x16x32_bf16(vf, pf,
                                                             oacc[g][dt], 0, 0, 0);
      }
    }

    __syncthreads();  // single barrier: drains prefetch (had full iter), frees bufs
    cur ^= 1;
  }

  // write fp32 unnormalized partials + (m,l)
#pragma unroll
  for (int g = 0; g < 2; ++g) {
    const size_t row = (size_t)split * BLQ + (size_t)batch * LQ + q0 +
                       wid * 32 + g * 16 + lr;
    float* Op = Opart + row * 128;
#pragma unroll
    for (int dt = 0; dt < 8; ++dt) {
      float4 o = {oacc[g][dt][0], oacc[g][dt][1], oacc[g][dt][2], oacc[g][dt][3]};
      *(float4*)(Op + dt * 16 + lg * 4) = o;
    }
    if (lane < 16) {
      Ml[row * 2 + 0] = m_run[g];
      Ml[row * 2 + 1] = l_run[g];
    }
  }
#undef STAGEKV
}

// ---------- combine KV-splits + output projection via MFMA ----------
__global__ __launch_bounds__(256) void combine_out_proj(
    const float* __restrict__ Opart, const float* __restrict__ Ml,
    const u16* __restrict__ WoT, const float* __restrict__ bo,
    float* __restrict__ out, int nsplit) {
  const int row0 = blockIdx.x * 64;
  const int tid = threadIdx.x;
  const int wid = tid >> 6;
  const int lane = tid & 63;
  const int lg = lane >> 4, lr = lane & 15;
  const int m = row0 + wid * 16 + lr;

  float M = -1e30f;
  for (int s = 0; s < nsplit; ++s)
    M = fmaxf(M, Ml[((size_t)s * BLQ + m) * 2 + 0]);
  float den = 0.f;
  for (int s = 0; s < nsplit; ++s)
    den += Ml[((size_t)s * BLQ + m) * 2 + 1] *
           exp2f(Ml[((size_t)s * BLQ + m) * 2 + 0] - M);
  const float invden = 1.f / den;

  float accO[4][8];
#pragma unroll
  for (int ks = 0; ks < 4; ++ks)
#pragma unroll
    for (int j = 0; j < 8; ++j) accO[ks][j] = 0.f;

  for (int s = 0; s < nsplit; ++s) {
    const float es = exp2f(Ml[((size_t)s * BLQ + m) * 2 + 0] - M) * invden;
    const float* Op = Opart + ((size_t)s * BLQ + m) * 128;
#pragma unroll
    for (int ks = 0; ks < 4; ++ks) {
      const float* p = Op + ks * 32 + lg * 8;
      const float4 a = *(const float4*)p;
      const float4 b = *(const float4*)(p + 4);
      accO[ks][0] += es * a.x; accO[ks][1] += es * a.y;
      accO[ks][2] += es * a.z; accO[ks][3] += es * a.w;
      accO[ks][4] += es * b.x; accO[ks][5] += es * b.y;
      accO[ks][6] += es * b.z; accO[ks][7] += es * b.w;
    }
  }

  bf16x8 ofrag[4];
#pragma unroll
  for (int ks = 0; ks < 4; ++ks) {
    Bf8Pack pk;
#pragma unroll
    for (int j = 0; j < 8; ++j) pk.u[j] = f2bf(accO[ks][j]);
    ofrag[ks] = pk.v;
  }

#pragma unroll
  for (int dt = 0; dt < 8; ++dt) {
    f32x4 acc = (f32x4){0.f, 0.f, 0.f, 0.f};
#pragma unroll
    for (int ks = 0; ks < 4; ++ks) {
      const bf16x8 wf =
          *(const bf16x8*)(WoT + (size_t)(dt * 16 + lr) * DOUT + ks * 32 + lg * 8);
      acc = __builtin_amdgcn_mfma_f32_16x16x32_bf16(wf, ofrag[ks], acc, 0, 0, 0);
    }
    float4 o;
    o.x = acc[0] + bo[dt * 16 + lg * 4 + 0];
    o.y = acc[1] + bo[dt * 16 + lg * 4 + 1];
    o.z = acc[2] + bo[dt * 16 + lg * 4 + 2];
    o.w = acc[3] + bo[dt * 16 + lg * 4 + 3];
    *(float4*)(out + (size_t)m * DOUT + dt * 16 + lg * 4) = o;
  }
}

extern "C" void kernel_launch(void* const* d_in, const int* in_sizes, int n_in,
                              void* d_out, int out_size, void* d_ws,
                              size_t ws_size, hipStream_t stream) {
  const float* ligand = (const float*)d_in[0];
  const float* pocket = (const float*)d_in[1];
  const float* Wq = (const float*)d_in[2];
  const float* bq = (const float*)d_in[3];
  const float* Wk = (const float*)d_in[4];
  const float* bk = (const float*)d_in[5];
  const float* Wv = (const float*)d_in[6];
  const float* bv = (const float*)d_in[7];
  const float* Wo = (const float*)d_in[8];
  const float* bo = (const float*)d_in[9];
  float* out = (float*)d_out;

  const size_t MB = 1024 * 1024;
  char* ws = (char*)d_ws;
  u16* Qb = (u16*)(ws);                      // 4 MB
  u16* Kb = (u16*)(ws + 4 * MB);             // 4 MB
  u16* Vt = (u16*)(ws + 8 * MB);             // 4 MB (V^T)
  u16* Wt = (u16*)(ws + 12 * MB);            // 192 KB
  u16* WoT = Wt + 3 * DOUT * DIN;            // 32 KB
  float* Opart = (float*)(ws + 13 * MB);     // ns * 8 MB
  const int ns = (ws_size >= 78 * MB) ? 8 : 4;
  float* Ml = (float*)(ws + 13 * MB + (size_t)ns * 8 * MB);  // ns*128KB

  wtrans_kernel<<<dim3(448), dim3(256), 0, stream>>>(Wq, Wk, Wv, Wo, Wt, WoT);

  dim3 g1(BLQ / 64, 3);
  qkv_proj_mfma<<<g1, dim3(256), 0, stream>>>(ligand, pocket, bq, bk, bv, Wt,
                                              Qb, Kb, Vt);

  dim3 g2(LQ / 128, B_SZ, ns);
  flash_attn_kernel<<<g2, dim3(256), 0, stream>>>(Qb, Kb, Vt, Opart, Ml,
                                                  NT / ns);

  dim3 g3(BLQ / 64);
  combine_out_proj<<<g3, dim3(256), 0, stream>>>(Opart, Ml, WoT, bo, out, ns);
}

// Round 8
// 116.501 us; speedup vs baseline: 1.1894x; 1.1823x over previous
//
#include <hip/hip_runtime.h>

#define B_SZ 4
#define LQ 4096
#define LKV 4096
#define DIN 256
#define DOUT 128
#define KVBLK 32
#define NT (LKV / KVBLK)
#define BLQ (B_SZ * LQ)
#define KTILE (KVBLK * 128)  // u16 elements per K or V tile (8 KB)

typedef unsigned short u16;
typedef __attribute__((ext_vector_type(8))) short bf16x8;
typedef __attribute__((ext_vector_type(4))) float f32x4;
typedef __attribute__((ext_vector_type(16))) float f32x16;

union Bf8Pack {
  u16 u[8];
  bf16x8 v;
};
union U16x4Pack {
  u16 u[4];
  uint2 v;
};
union PFrag {
  unsigned u[4];
  bf16x8 v;
};

__device__ __forceinline__ u16 f2bf(float x) {
  unsigned u = __float_as_uint(x);
  u += 0x7fffu + ((u >> 16) & 1u);
  return (u16)(u >> 16);
}

__device__ __forceinline__ float bf2f(u16 x) {
  return __uint_as_float(((unsigned)x) << 16);
}

__device__ __forceinline__ unsigned cvt_pk_bf16(float lo, float hi) {
  unsigned r;
  asm("v_cvt_pk_bf16_f32 %0, %1, %2" : "=v"(r) : "v"(lo), "v"(hi));
  return r;
}

__device__ __forceinline__ void gload_lds16(const u16* g, u16* l) {
  __builtin_amdgcn_global_load_lds(
      (__attribute__((address_space(1))) unsigned int*)g,
      (__attribute__((address_space(3))) unsigned int*)l, 16, 0, 0);
}

// ---------- weight transpose + bf16 convert: Wt[3][128][256], WoT[128][128] ----------
__global__ __launch_bounds__(256) void wtrans_kernel(
    const float* __restrict__ Wq, const float* __restrict__ Wk,
    const float* __restrict__ Wv, const float* __restrict__ Wo,
    u16* __restrict__ Wt, u16* __restrict__ WoT) {
  const int gid = blockIdx.x * 256 + threadIdx.x;
  if (gid < 3 * DOUT * DIN) {
    const int which = gid / (DOUT * DIN);
    const int r = gid % (DOUT * DIN);
    const int n = r >> 8;
    const int k = r & 255;
    const float* W = (which == 0) ? Wq : (which == 1) ? Wk : Wv;
    Wt[gid] = f2bf(W[k * DOUT + n]);
  } else {
    const int r = gid - 3 * DOUT * DIN;
    if (r < DOUT * DOUT) {
      const int n = r >> 7;
      const int k = r & 127;
      WoT[r] = f2bf(Wo[k * DOUT + n]);
    }
  }
}

// ---------- QKV projection via MFMA (16x16x32, proven) ----------
__global__ __launch_bounds__(256) void qkv_proj_mfma(
    const float* __restrict__ ligand, const float* __restrict__ pocket,
    const float* __restrict__ bq, const float* __restrict__ bk,
    const float* __restrict__ bv, const u16* __restrict__ Wt,
    u16* __restrict__ Qb, u16* __restrict__ Kb, u16* __restrict__ Vt) {
  const int which = blockIdx.y;
  const int row0 = blockIdx.x * 64;
  const int tid = threadIdx.x;
  const int wid = tid >> 6;
  const int lane = tid & 63;
  const int lg = lane >> 4, lr = lane & 15;
  const float* __restrict__ src = (which == 0) ? ligand : pocket;
  const int m = row0 + wid * 16 + lr;

  bf16x8 sfrag[8];
#pragma unroll
  for (int ks = 0; ks < 8; ++ks) {
    const float* p = src + (size_t)m * DIN + ks * 32 + lg * 8;
    const float4 a = *(const float4*)p;
    const float4 b = *(const float4*)(p + 4);
    Bf8Pack pk;
    pk.u[0] = f2bf(a.x); pk.u[1] = f2bf(a.y); pk.u[2] = f2bf(a.z); pk.u[3] = f2bf(a.w);
    pk.u[4] = f2bf(b.x); pk.u[5] = f2bf(b.y); pk.u[6] = f2bf(b.z); pk.u[7] = f2bf(b.w);
    sfrag[ks] = pk.v;
  }

  const u16* __restrict__ Wtw = Wt + (size_t)which * DOUT * DIN;

  if (which < 2) {
    const float* __restrict__ bias = (which == 0) ? bq : bk;
    u16* __restrict__ dst = (which == 0) ? Qb : Kb;
    // Q pre-scaled by 1/sqrt(128) * log2(e): flash uses exp2 with fixed m=0.
    const float qscale = (float)(0.08838834764831845 * 1.4426950408889634);
#pragma unroll
    for (int dt = 0; dt < 8; ++dt) {
      f32x4 acc = (f32x4){0.f, 0.f, 0.f, 0.f};
#pragma unroll
      for (int ks = 0; ks < 8; ++ks) {
        const bf16x8 wf =
            *(const bf16x8*)(Wtw + (size_t)(dt * 16 + lr) * DIN + ks * 32 + lg * 8);
        acc = __builtin_amdgcn_mfma_f32_16x16x32_bf16(wf, sfrag[ks], acc, 0, 0, 0);
      }
      U16x4Pack st;
#pragma unroll
      for (int j = 0; j < 4; ++j) {
        const int d = dt * 16 + lg * 4 + j;
        float v = acc[j] + bias[d];
        if (which == 0) v *= qscale;
        st.u[j] = f2bf(v);
      }
      *(uint2*)(dst + (size_t)m * DOUT + dt * 16 + lg * 4) = st.v;
    }
  } else {
    const int batch = row0 >> 12;
    const int kvbase = (row0 & 4095) + wid * 16 + lg * 4;
#pragma unroll
    for (int dt = 0; dt < 8; ++dt) {
      f32x4 acc = (f32x4){0.f, 0.f, 0.f, 0.f};
#pragma unroll
      for (int ks = 0; ks < 8; ++ks) {
        const bf16x8 wf =
            *(const bf16x8*)(Wtw + (size_t)(dt * 16 + lr) * DIN + ks * 32 + lg * 8);
        acc = __builtin_amdgcn_mfma_f32_16x16x32_bf16(sfrag[ks], wf, acc, 0, 0, 0);
      }
      const int d = dt * 16 + lr;
      const float b = bv[d];
      U16x4Pack st;
#pragma unroll
      for (int j = 0; j < 4; ++j) st.u[j] = f2bf(acc[j] + b);
      *(uint2*)(Vt + ((size_t)batch * DOUT + d) * LKV + kvbase) = st.v;
    }
  }
}

// ---------------- Flash attention: 32x32x16 MFMA, P in-register via permlane ----------------
// Block = 4 waves; wave owns 32 q-rows (q = lane&31). KVBLK = 32; fixed m = 0.
// LDS K tile: slot[ks][l] (16B) = K[kv=l&31][ks*16 + (l>>5)*8 ..+8], ks=0..7
// LDS V tile: slot[dt*2+ks][l] = V^T[dt*32+(l&31)][ks*16 + (l>>5)*8 ..+8]
// QK: sacc = mfma32x32x16(Kfrag, Qfrag): lane holds S[kv=(r&3)+8(r>>2)+4h][q=lane&31]
// P: cvt_pk pairs + permlane32_swap (D-high<->S-low) -> A/B frag (D1,D2,S1,S2)
// PV: oacc[dt] = mfma(Vfrag, Pfrag): lane holds O[q=lane&31][d=dt*32+(r&3)+8(r>>2)+4h]
__global__ __launch_bounds__(256, 4) void flash_attn_kernel(
    const u16* __restrict__ Qb, const u16* __restrict__ Kb,
    const u16* __restrict__ Vt, u16* __restrict__ Opart,
    float* __restrict__ Lsum, int niter) {
  __shared__ __align__(16) u16 Ks[2 * KTILE];
  __shared__ __align__(16) u16 Vs[2 * KTILE];

  const int batch = blockIdx.y;
  const int split = blockIdx.z;
  const int q0 = blockIdx.x * 128;
  const int tid = threadIdx.x;
  const int wid = tid >> 6;
  const int lane = tid & 63;
  const int ql = lane & 31;
  const int h = lane >> 5;
  const int t0 = split * niter;

  // staging source offsets (u16 elements): 512 chunks/tile, 2 per thread
  int koff[2], voff[2];
#pragma unroll
  for (int i = 0; i < 2; ++i) {
    const int c = i * 256 + tid;
    koff[i] = (c & 31) * 128 + (c >> 6) * 16 + ((c >> 5) & 1) * 8;
    voff[i] = ((c >> 7) * 32 + (c & 31)) * LKV + (((c >> 6) & 1) << 4) +
              (((c >> 5) & 1) << 3);
  }
  const u16* KbB = Kb + (size_t)batch * LKV * 128 + (size_t)t0 * KTILE;
  const u16* VtB = Vt + (size_t)batch * 128 * LKV + t0 * KVBLK;

#define STAGEKV(buf, t)                                                      \
  {                                                                          \
    _Pragma("unroll") for (int i = 0; i < 2; ++i)                            \
        gload_lds16(KbB + (t) * KTILE + koff[i],                             \
                    Ks + (buf) * KTILE + (i * 256 + tid) * 8);               \
    _Pragma("unroll") for (int i = 0; i < 2; ++i)                            \
        gload_lds16(VtB + (t) * KVBLK + voff[i],                             \
                    Vs + (buf) * KTILE + (i * 256 + tid) * 8);               \
  }

  // Q fragments: lane holds Q[q0+wid*32+ql][ks*16 + h*8 ..+8], ks=0..7
  const u16* Qw = Qb + ((size_t)batch * LQ + q0 + wid * 32) * 128;
  bf16x8 qf[8];
#pragma unroll
  for (int ks = 0; ks < 8; ++ks)
    qf[ks] = *(const bf16x8*)(Qw + (size_t)ql * 128 + ks * 16 + h * 8);

  f32x16 oacc[4];
#pragma unroll
  for (int dt = 0; dt < 4; ++dt)
#pragma unroll
    for (int r = 0; r < 16; ++r) oacc[dt][r] = 0.f;
  float l_run = 0.f;

  STAGEKV(0, 0);
  __syncthreads();

  int cur = 0;
  for (int t = 0; t < niter; ++t) {
    if (t + 1 < niter) STAGEKV(cur ^ 1, t + 1);

    const u16* kread = Ks + cur * KTILE + lane * 8;
    const u16* vread = Vs + cur * KTILE + lane * 8;

    // S = K · Q^T  (D[kv][q], col q = lane&31)
    f32x16 sacc;
#pragma unroll
    for (int r = 0; r < 16; ++r) sacc[r] = 0.f;
#pragma unroll
    for (int ks = 0; ks < 8; ++ks) {
      const bf16x8 kf = *(const bf16x8*)(kread + ks * 512);
      sacc = __builtin_amdgcn_mfma_f32_32x32x16_bf16(kf, qf[ks], sacc, 0, 0, 0);
    }

    // fixed-m softmax: p = exp2(min(s,60)); row sum across reg-half + partner
    float p[16];
    float rs = 0.f;
#pragma unroll
    for (int r = 0; r < 16; ++r) {
      p[r] = exp2f(fminf(sacc[r], 60.f));
      rs += p[r];
    }
    rs += __shfl_xor(rs, 32, 64);
    l_run += rs;

    // pack P to bf16 pairs, redistribute halves via permlane32_swap
    unsigned w0 = cvt_pk_bf16(p[0], p[1]);
    unsigned w1 = cvt_pk_bf16(p[2], p[3]);
    unsigned w2 = cvt_pk_bf16(p[4], p[5]);
    unsigned w3 = cvt_pk_bf16(p[6], p[7]);
    unsigned w4 = cvt_pk_bf16(p[8], p[9]);
    unsigned w5 = cvt_pk_bf16(p[10], p[11]);
    unsigned w6 = cvt_pk_bf16(p[12], p[13]);
    unsigned w7 = cvt_pk_bf16(p[14], p[15]);
    asm("v_permlane32_swap_b32 %0, %1" : "+v"(w0), "+v"(w2));
    asm("v_permlane32_swap_b32 %0, %1" : "+v"(w1), "+v"(w3));
    asm("v_permlane32_swap_b32 %0, %1" : "+v"(w4), "+v"(w6));
    asm("v_permlane32_swap_b32 %0, %1" : "+v"(w5), "+v"(w7));
    PFrag pa0, pa1;
    pa0.u[0] = w0; pa0.u[1] = w1; pa0.u[2] = w2; pa0.u[3] = w3;  // kv 0..15
    pa1.u[0] = w4; pa1.u[1] = w5; pa1.u[2] = w6; pa1.u[3] = w7;  // kv 16..31

    // O^T += V^T · P^T  (A = V^T frag from LDS, B = P frag in reg)
#pragma unroll
    for (int dt = 0; dt < 4; ++dt) {
      const bf16x8 vf0 = *(const bf16x8*)(vread + (dt * 2 + 0) * 512);
      oacc[dt] = __builtin_amdgcn_mfma_f32_32x32x16_bf16(vf0, pa0.v, oacc[dt], 0, 0, 0);
      const bf16x8 vf1 = *(const bf16x8*)(vread + (dt * 2 + 1) * 512);
      oacc[dt] = __builtin_amdgcn_mfma_f32_32x32x16_bf16(vf1, pa1.v, oacc[dt], 0, 0, 0);
    }

    __syncthreads();
    cur ^= 1;
  }

  // write bf16 unnormalized partials + row sums (m = 0 global)
  const size_t rowbase = (size_t)split * BLQ + (size_t)batch * LQ + q0 + wid * 32;
  u16* Op = Opart + (rowbase + ql) * 128;
#pragma unroll
  for (int dt = 0; dt < 4; ++dt)
#pragma unroll
    for (int g2 = 0; g2 < 4; ++g2) {
      uint2 st;
      st.x = cvt_pk_bf16(oacc[dt][g2 * 4 + 0], oacc[dt][g2 * 4 + 1]);
      st.y = cvt_pk_bf16(oacc[dt][g2 * 4 + 2], oacc[dt][g2 * 4 + 3]);
      *(uint2*)(Op + dt * 32 + g2 * 8 + h * 4) = st;
    }
  if (lane < 32) Lsum[rowbase + lane] = l_run;
#undef STAGEKV
}

// ---------- combine KV-splits (linear, m=0) + output projection via MFMA ----------
__global__ __launch_bounds__(256) void combine_out_proj(
    const u16* __restrict__ Opart, const float* __restrict__ Lsum,
    const u16* __restrict__ WoT, const float* __restrict__ bo,
    float* __restrict__ out, int nsplit) {
  const int row0 = blockIdx.x * 64;
  const int tid = threadIdx.x;
  const int wid = tid >> 6;
  const int lane = tid & 63;
  const int lg = lane >> 4, lr = lane & 15;
  const int m = row0 + wid * 16 + lr;

  float den = 0.f;
  for (int s = 0; s < nsplit; ++s) den += Lsum[(size_t)s * BLQ + m];
  const float inv = 1.f / den;

  float accO[4][8];
#pragma unroll
  for (int ks = 0; ks < 4; ++ks)
#pragma unroll
    for (int j = 0; j < 8; ++j) accO[ks][j] = 0.f;

  for (int s = 0; s < nsplit; ++s) {
    const u16* Op = Opart + ((size_t)s * BLQ + m) * 128;
#pragma unroll
    for (int ks = 0; ks < 4; ++ks) {
      const uint4 v = *(const uint4*)(Op + ks * 32 + lg * 8);
      accO[ks][0] += bf2f((u16)(v.x & 0xffff));
      accO[ks][1] += bf2f((u16)(v.x >> 16));
      accO[ks][2] += bf2f((u16)(v.y & 0xffff));
      accO[ks][3] += bf2f((u16)(v.y >> 16));
      accO[ks][4] += bf2f((u16)(v.z & 0xffff));
      accO[ks][5] += bf2f((u16)(v.z >> 16));
      accO[ks][6] += bf2f((u16)(v.w & 0xffff));
      accO[ks][7] += bf2f((u16)(v.w >> 16));
    }
  }

  bf16x8 ofrag[4];
#pragma unroll
  for (int ks = 0; ks < 4; ++ks) {
    Bf8Pack pk;
#pragma unroll
    for (int j = 0; j < 8; ++j) pk.u[j] = f2bf(accO[ks][j] * inv);
    ofrag[ks] = pk.v;
  }

#pragma unroll
  for (int dt = 0; dt < 8; ++dt) {
    f32x4 acc = (f32x4){0.f, 0.f, 0.f, 0.f};
#pragma unroll
    for (int ks = 0; ks < 4; ++ks) {
      const bf16x8 wf =
          *(const bf16x8*)(WoT + (size_t)(dt * 16 + lr) * DOUT + ks * 32 + lg * 8);
      acc = __builtin_amdgcn_mfma_f32_16x16x32_bf16(wf, ofrag[ks], acc, 0, 0, 0);
    }
    float4 o;
    o.x = acc[0] + bo[dt * 16 + lg * 4 + 0];
    o.y = acc[1] + bo[dt * 16 + lg * 4 + 1];
    o.z = acc[2] + bo[dt * 16 + lg * 4 + 2];
    o.w = acc[3] + bo[dt * 16 + lg * 4 + 3];
    *(float4*)(out + (size_t)m * DOUT + dt * 16 + lg * 4) = o;
  }
}

extern "C" void kernel_launch(void* const* d_in, const int* in_sizes, int n_in,
                              void* d_out, int out_size, void* d_ws,
                              size_t ws_size, hipStream_t stream) {
  const float* ligand = (const float*)d_in[0];
  const float* pocket = (const float*)d_in[1];
  const float* Wq = (const float*)d_in[2];
  const float* bq = (const float*)d_in[3];
  const float* Wk = (const float*)d_in[4];
  const float* bk = (const float*)d_in[5];
  const float* Wv = (const float*)d_in[6];
  const float* bv = (const float*)d_in[7];
  const float* Wo = (const float*)d_in[8];
  const float* bo = (const float*)d_in[9];
  float* out = (float*)d_out;

  const size_t MB = 1024 * 1024;
  char* ws = (char*)d_ws;
  u16* Qb = (u16*)(ws);                      // 4 MB
  u16* Kb = (u16*)(ws + 4 * MB);             // 4 MB
  u16* Vt = (u16*)(ws + 8 * MB);             // 4 MB (V^T)
  u16* Wt = (u16*)(ws + 12 * MB);            // 192 KB
  u16* WoT = Wt + 3 * DOUT * DIN;            // 32 KB
  const int ns = (ws_size >= 46 * MB) ? 8 : 4;
  u16* Opart = (u16*)(ws + 13 * MB);                            // ns*4 MB bf16
  float* Lsum = (float*)(ws + 13 * MB + (size_t)ns * 4 * MB);   // ns*64 KB

  wtrans_kernel<<<dim3(448), dim3(256), 0, stream>>>(Wq, Wk, Wv, Wo, Wt, WoT);

  dim3 g1(BLQ / 64, 3);
  qkv_proj_mfma<<<g1, dim3(256), 0, stream>>>(ligand, pocket, bq, bk, bv, Wt,
                                              Qb, Kb, Vt);

  dim3 g2(LQ / 128, B_SZ, ns);
  flash_attn_kernel<<<g2, dim3(256), 0, stream>>>(Qb, Kb, Vt, Opart, Lsum,
                                                  NT / ns);

  dim3 g3(BLQ / 64);
  combine_out_proj<<<g3, dim3(256), 0, stream>>>(Opart, Lsum, WoT, bo, out, ns);
}